// Round 12
// baseline (209.328 us; speedup 1.0000x reference)
//
#include <hip/hip_runtime.h>

// GIN forward: transformed-space linearity (y = h@wa; agg@wa = y_self + sum y_nbr)
// fp16 activation tables (y, t, z, h3), CSR via bucket binning + packed
// counting sort (local bucket-base rescan, no top-scan dispatch), fused
// setup kernel (hist || wfrag || gptr || pre), wave-per-node gather agg
// (8-deep + 2-pad tail) with fused BN+ReLU, MFMA-f16 MLP with pre-fragmented
// weights (3 waves/EU), per-graph fused pool+head.
// N=100000, E=1200000, DIM=64, G=1000, IN=11.

#define BN_EPS 1e-5f
#define NBUCK 512
#define NBLK  256

typedef __attribute__((ext_vector_type(8))) _Float16 half8v;  // 8 f16 (4 VGPRs)
typedef __attribute__((ext_vector_type(4))) float float4v;    // 4 fp32 acc

// ---- setup: blocks [0,256) hist, [256,261) wfrag, [261,261+GB) gptr, rest pre
__global__ __launch_bounds__(256)
void setup_kernel(const int* __restrict__ dst, int* __restrict__ ghist,
                  int E, int chunk, _Float16* __restrict__ yrow,
                  const int* __restrict__ batch, int* __restrict__ gptr,
                  int N, int G,
                  const float* __restrict__ x, const float* __restrict__ w1a,
                  _Float16* __restrict__ yh,
                  const float* __restrict__ wf0, const float* __restrict__ wf1,
                  const float* __restrict__ wf2, const float* __restrict__ wf3,
                  const float* __restrict__ wf4, _Float16* __restrict__ fwout,
                  int nGptrBlocks, int nPreBlocks) {
    __shared__ int h[NBUCK];
    __shared__ float s_wa[11 * 64];
    __shared__ float s_row[4][11];
    const int blk = blockIdx.x, tid = threadIdx.x;

    if (blk < NBLK) {
        // ---- histogram (bucket-major) + zero pad row ----
        if (blk == 0 && tid < 64) yrow[tid] = (_Float16)0.f;
        for (int u = tid; u < NBUCK; u += 256) h[u] = 0;
        __syncthreads();
        const int e0 = blk * chunk, e1 = min(E, e0 + chunk);
        for (int e = e0 + tid; e < e1; e += 256)
            atomicAdd(&h[dst[e] >> 8], 1);
        __syncthreads();
        for (int u = tid; u < NBUCK; u += 256)
            ghist[u * NBLK + blk] = h[u];
    } else if (blk < NBLK + 5) {
        // ---- weight fragmenting: fp32 64x64 -> fp16 B-fragment order ----
        const int m = blk - NBLK;
        const float* w = (m == 0) ? wf0 : (m == 1) ? wf1 : (m == 2) ? wf2 :
                         (m == 3) ? wf3 : wf4;
        _Float16* o = fwout + (size_t)m * 4096;
        const int lane = tid & 63;
        const int cb   = tid >> 6;
        const int half = lane >> 4, sub = lane & 15;
        #pragma unroll
        for (int it = 0; it < 2; ++it) {
            int c = cb + 4 * it;             // 0..7 = kk*4 + nt
            int kk = c >> 2, nt = c & 3;
            _Float16 f[8];
            #pragma unroll
            for (int j = 0; j < 8; ++j)
                f[j] = (_Float16)w[(kk * 32 + half * 8 + j) * 64 + nt * 16 + sub];
            *(half8v*)&o[((size_t)c * 64 + lane) * 8] = *(half8v*)f;
        }
    } else if (blk < NBLK + 5 + nGptrBlocks) {
        // ---- graph boundaries (batch sorted) ----
        int i = (blk - NBLK - 5) * 256 + tid;
        if (i < N) {
            int b = batch[i];
            int bprev = (i == 0) ? -1 : batch[i - 1];
            for (int g = bprev + 1; g <= b; ++g) gptr[g] = i;
            if (i == N - 1)
                for (int g = b + 1; g <= G; ++g) gptr[g] = N;
        }
    } else {
        // ---- pre-transform: yh = f16(x @ w1a) ----
        const int pb = blk - NBLK - 5 - nGptrBlocks;
        const int lane = tid & 63;
        const int local = tid >> 6;
        for (int i = tid; i < 11 * 64; i += 256) s_wa[i] = w1a[i];
        __syncthreads();
        const int groups = (N + 3) >> 2;
        for (int grp = pb; grp < groups; grp += nPreBlocks) {
            const int node = grp * 4 + local;
            if (node >= N) continue;
            if (lane < 11) s_row[local][lane] = x[(size_t)node * 11 + lane];
            float acc = 0.f;
            #pragma unroll
            for (int k = 0; k < 11; ++k)
                acc = fmaf(s_row[local][k], s_wa[k * 64 + lane], acc);
            yh[((size_t)node << 6) + lane] = (_Float16)acc;
        }
    }
}

// ---------------- per-chunk exclusive scan (chunk = bucket) ----------------
__global__ __launch_bounds__(256)
void scan_block_g(int* __restrict__ a, int* __restrict__ bsum, int n) {
    __shared__ int s[256];
    int i = blockIdx.x * 256 + threadIdx.x;
    int v = (i < n) ? a[i] : 0;
    s[threadIdx.x] = v;
    __syncthreads();
    for (int off = 1; off < 256; off <<= 1) {
        int t = (threadIdx.x >= off) ? s[threadIdx.x - off] : 0;
        __syncthreads();
        s[threadIdx.x] += t;
        __syncthreads();
    }
    if (i < n) a[i] = s[threadIdx.x] - v;
    if (threadIdx.x == 255) bsum[blockIdx.x] = s[255];
}

// ------- bin fill: local bucket-base scan + LDS cursors -> packed writes ---
// packed pair: (dstLocal << 24) | src   (src < 2^24)
__global__ __launch_bounds__(256)
void bin_fill_kernel(const int* __restrict__ src, const int* __restrict__ dst,
                     const int* __restrict__ ghist, const int* __restrict__ bsumRaw,
                     unsigned* __restrict__ pairs, int E, int chunk) {
    __shared__ int cur[NBUCK];
    __shared__ int ps[256];
    const int t = threadIdx.x, blk = blockIdx.x;
    // exclusive scan of bsumRaw[512] (pair-per-thread)
    int a0 = bsumRaw[2 * t], a1 = bsumRaw[2 * t + 1];
    ps[t] = a0 + a1;
    __syncthreads();
    for (int off = 1; off < 256; off <<= 1) {
        int v = (t >= off) ? ps[t - off] : 0;
        __syncthreads();
        ps[t] += v;
        __syncthreads();
    }
    const int pb = ps[t] - (a0 + a1);
    cur[2 * t]     = pb      + ghist[(2 * t) * NBLK + blk];
    cur[2 * t + 1] = pb + a0 + ghist[(2 * t + 1) * NBLK + blk];
    __syncthreads();
    const int e0 = blk * chunk, e1 = min(E, e0 + chunk);
    for (int e = e0 + t; e < e1; e += 256) {
        int d = dst[e];
        int pos = atomicAdd(&cur[d >> 8], 1);
        pairs[pos] = ((unsigned)(d & 255) << 24) | (unsigned)src[e];
    }
}

// ------- per-bucket counting sort -> per-node CSR (col, rp) ----------------
__global__ __launch_bounds__(256)
void csr_sort_kernel(const unsigned* __restrict__ pairs, const int* __restrict__ bsumRaw,
                     int* __restrict__ col, int* __restrict__ rp,
                     int N, int E, int nbuckUsed) {
    __shared__ int sb[NBUCK + 1];
    __shared__ int cnt[256];
    __shared__ int cur[256];
    const int u = blockIdx.x, tid = threadIdx.x;
    // local exclusive scan of bsumRaw[512] -> bucket bases
    {
        int a0 = bsumRaw[2 * tid], a1 = bsumRaw[2 * tid + 1];
        cnt[tid] = a0 + a1;
        __syncthreads();
        for (int off = 1; off < 256; off <<= 1) {
            int v = (tid >= off) ? cnt[tid - off] : 0;
            __syncthreads();
            cnt[tid] += v;
            __syncthreads();
        }
        int pb = cnt[tid] - (a0 + a1);
        sb[2 * tid] = pb;
        sb[2 * tid + 1] = pb + a0;
        if (tid == 255) sb[NBUCK] = E;
        __syncthreads();
    }
    const int base = sb[u];
    const int end  = sb[u + 1];
    const int node0 = u << 8;
    const int rows = min(256, N - node0);

    cnt[tid] = 0;
    __syncthreads();
    for (int e = base + tid; e < end; e += 256)
        atomicAdd(&cnt[pairs[e] >> 24], 1);
    __syncthreads();
    int own = cnt[tid];
    __syncthreads();
    cnt[tid] = own;
    __syncthreads();
    for (int off = 1; off < 256; off <<= 1) {
        int t = (tid >= off) ? cnt[tid - off] : 0;
        __syncthreads();
        cnt[tid] += t;
        __syncthreads();
    }
    const int excl = cnt[tid] - own;
    if (tid < rows) rp[node0 + tid] = base + excl;
    if (tid == 0 && u == nbuckUsed - 1) rp[N] = E;
    cur[tid] = base + excl;
    __syncthreads();
    for (int e = base + tid; e < end; e += 256) {
        unsigned p = pairs[e];
        int pos = atomicAdd(&cur[p >> 24], 1);
        col[pos] = (int)(p & 0xFFFFFF);
    }
}

// -- aggregate + BN + ReLU: t[i] = relu(bn(y[i] + sum_nbr y[j]) + ba) -------
// wave = node (uniform), lane = feature; 8-deep main + 2-pad tail.
__global__ __launch_bounds__(256, 8)
void agg_kernel(const _Float16* __restrict__ yh, const int* __restrict__ rp,
                const int* __restrict__ col,
                const float* __restrict__ ba,
                const float* __restrict__ gam, const float* __restrict__ bet,
                const float* __restrict__ rm, const float* __restrict__ rv,
                _Float16* __restrict__ th, int n) {
    int node = __builtin_amdgcn_readfirstlane(
        (int)((blockIdx.x * 256 + threadIdx.x) >> 6));
    if (node >= n) return;
    const int lane = threadIdx.x & 63;
    const int beg = rp[node], end = rp[node + 1];
    float agg = (float)yh[((size_t)node << 6) + lane];
    int i = beg;
    const int end8 = beg + ((end - beg) & ~7);
    for (; i < end8; i += 8) {
        int c[8];
        float v[8];
        #pragma unroll
        for (int j = 0; j < 8; ++j) c[j] = col[i + j];
        #pragma unroll
        for (int j = 0; j < 8; ++j) v[j] = (float)yh[((size_t)c[j] << 6) + lane];
        #pragma unroll
        for (int j = 0; j < 8; ++j) agg += v[j];
    }
    for (; i < end; i += 2) {
        int c0 = col[i];
        int c1 = (i + 1 < end) ? col[i + 1] : n;
        float v0 = (float)yh[((size_t)c0 << 6) + lane];
        float v1 = (float)yh[((size_t)c1 << 6) + lane];
        agg += v0;
        agg += v1;
    }
    const float s = gam[lane] * rsqrtf(rv[lane] + BN_EPS);
    const float sh = bet[lane] - rm[lane] * s + ba[lane] * s;
    th[((size_t)node << 6) + lane] = (_Float16)fmaxf(fmaf(agg, s, sh), 0.f);
}

// ------------- MFMA MLP: z=relu(t@wb+bb); y'=f16(z@wn) / h3=f16(z) ---------
template<bool LAST>
__global__ __launch_bounds__(256, 3)
void mlp_mfma_kernel(const _Float16* __restrict__ th,   // [n,64] t fp16
                     const _Float16* __restrict__ fwb,  // [8][64][8] frag
                     const float* __restrict__ bb,
                     const _Float16* __restrict__ fwn,  // [8][64][8] frag
                     _Float16* __restrict__ outh, int n) {
    __shared__ _Float16 zt[4][16][72];   // per-wave z tile, 144B stride

    const int tid  = threadIdx.x;
    const int lane = tid & 63;
    const int w    = tid >> 6;
    const int half = lane >> 4;    // k-group / row-group
    const int sub  = lane & 15;    // row (A) / col (C)

    half8v wbf[2][4];
    #pragma unroll
    for (int kk = 0; kk < 2; ++kk)
        #pragma unroll
        for (int nt = 0; nt < 4; ++nt)
            wbf[kk][nt] = *(const half8v*)&fwb[(((size_t)(kk * 4 + nt)) * 64 + lane) * 8];
    half8v wnf[LAST ? 1 : 2][4];
    if (!LAST) {
        #pragma unroll
        for (int kk = 0; kk < 2; ++kk)
            #pragma unroll
            for (int nt = 0; nt < 4; ++nt)
                wnf[kk][nt] = *(const half8v*)&fwn[(((size_t)(kk * 4 + nt)) * 64 + lane) * 8];
    }
    float bbr[4];
    #pragma unroll
    for (int nt = 0; nt < 4; ++nt) bbr[nt] = bb[nt * 16 + sub];

    const int ngroups = (n + 15) >> 4;
    const int stride = gridDim.x * 4;
    for (int group = blockIdx.x * 4 + w; group < ngroups; group += stride) {
        const int node0 = group << 4;
        int mrow = node0 + sub;
        if (mrow >= n) mrow = n - 1;              // stores are guarded

        half8v at[2];
        #pragma unroll
        for (int kk = 0; kk < 2; ++kk)
            at[kk] = *(const half8v*)&th[((size_t)mrow << 6) + kk * 32 + half * 8];

        float4v accz[4];
        #pragma unroll
        for (int nt = 0; nt < 4; ++nt) {
            float4v c = {0.f, 0.f, 0.f, 0.f};
            c = __builtin_amdgcn_mfma_f32_16x16x32_f16(at[0], wbf[0][nt], c, 0, 0, 0);
            c = __builtin_amdgcn_mfma_f32_16x16x32_f16(at[1], wbf[1][nt], c, 0, 0, 0);
            accz[nt] = c;
        }

        if (LAST) {
            #pragma unroll
            for (int nt = 0; nt < 4; ++nt)
                #pragma unroll
                for (int r = 0; r < 4; ++r) {
                    int m = node0 + half * 4 + r;
                    if (m < n)
                        outh[((size_t)m << 6) + nt * 16 + sub] =
                            (_Float16)fmaxf(accz[nt][r] + bbr[nt], 0.f);
                }
        } else {
            #pragma unroll
            for (int nt = 0; nt < 4; ++nt)
                #pragma unroll
                for (int r = 0; r < 4; ++r)
                    zt[w][half * 4 + r][nt * 16 + sub] =
                        (_Float16)fmaxf(accz[nt][r] + bbr[nt], 0.f);
            asm volatile("s_waitcnt lgkmcnt(0)" ::: "memory");
            __builtin_amdgcn_sched_barrier(0);
            half8v az[2];
            #pragma unroll
            for (int kk = 0; kk < 2; ++kk)
                az[kk] = *(const half8v*)&zt[w][sub][kk * 32 + half * 8];

            #pragma unroll
            for (int nt = 0; nt < 4; ++nt) {
                float4v c = {0.f, 0.f, 0.f, 0.f};
                c = __builtin_amdgcn_mfma_f32_16x16x32_f16(az[0], wnf[0][nt], c, 0, 0, 0);
                c = __builtin_amdgcn_mfma_f32_16x16x32_f16(az[1], wnf[1][nt], c, 0, 0, 0);
                #pragma unroll
                for (int r = 0; r < 4; ++r) {
                    int m = node0 + half * 4 + r;
                    if (m < n)
                        outh[((size_t)m << 6) + nt * 16 + sub] = (_Float16)c[r];
                }
            }
        }
    }
}

// ------- fused pool+head: block = graph; pool rows, then head math ---------
__global__ __launch_bounds__(64)
void pool_head_kernel(const _Float16* __restrict__ h, const int* __restrict__ gptr,
                      const float* __restrict__ lw1, const float* __restrict__ lb1,
                      const float* __restrict__ lw2, const float* __restrict__ lb2,
                      float* __restrict__ out, int G) {
    __shared__ float s_row[64];
    const int g = blockIdx.x;
    if (g >= G) return;
    const int d = threadIdx.x;
    const int beg = gptr[g], end = gptr[g + 1];

    float acc = 0.f;
    int i = beg;
    const int end4 = beg + ((end - beg) & ~3);
    for (; i < end4; i += 4) {
        float v0 = (float)h[((size_t)(i + 0) << 6) + d];
        float v1 = (float)h[((size_t)(i + 1) << 6) + d];
        float v2 = (float)h[((size_t)(i + 2) << 6) + d];
        float v3 = (float)h[((size_t)(i + 3) << 6) + d];
        acc += v0 + v1 + v2 + v3;
    }
    for (; i < end; ++i) acc += (float)h[((size_t)i << 6) + d];

    s_row[d] = acc;
    __syncthreads();

    float z = lb1[d];
    #pragma unroll 8
    for (int k = 0; k < 64; ++k)
        z = fmaf(s_row[k], lw1[k * 64 + d], z);
    z = fmaxf(z, 0.f);
    float r = z * lw2[d];
    #pragma unroll
    for (int off = 32; off > 0; off >>= 1)
        r += __shfl_down(r, off, 64);
    if (d == 0) out[g] = r + lb2[0];
}

extern "C" void kernel_launch(void* const* d_in, const int* in_sizes, int n_in,
                              void* d_out, int out_size, void* d_ws, size_t ws_size,
                              hipStream_t stream) {
    const float* x    = (const float*)d_in[0];
    const int* ei     = (const int*)d_in[1];
    const int* batch  = (const int*)d_in[2];
    const int N = in_sizes[0] / 11;
    const int E = in_sizes[1] / 2;
    const int G = out_size;
    const int* src = ei;
    const int* dst = ei + E;

    const float* p[28];
    for (int i = 0; i < 28; ++i) p[i] = (const float*)d_in[3 + i];
    // p[0..7]=L1 {wa,ba,g,be,m,v,wb,bb}, p[8..15]=L2, p[16..23]=L3
    // p[24]=lw1 p[25]=lb1 p[26]=lw2 p[27]=lb2

    _Float16* yh  = (_Float16*)d_ws;                     // [(N+1),64] fp16 y
    _Float16* th  = yh + ((size_t)N + 1) * 64;           // [N,64] fp16 t
    _Float16* h3h = th + (size_t)N * 64;                 // [N,64] fp16 h3
    _Float16* fw  = h3h + (size_t)N * 64;                // [5*4096] weight frags
    int*   ghist  = (int*)(fw + 5 * 4096);               // [NBUCK*NBLK]
    int*   bsum   = ghist + NBUCK * NBLK;                // [512] raw chunk totals
    int*   rp     = bsum + 512;                          // [N+1]
    int*   gptr   = rp + N + 1;                          // [G+1]
    int*   col    = gptr + G + 1;                        // [E]
    unsigned* pairs = (unsigned*)(col + E);              // [E] packed

    const int chunk     = (E + NBLK - 1) / NBLK;
    const int nscan     = NBUCK * NBLK;
    const int nbScanB   = nscan / 256;                   // 512
    const int nbuckUsed = (N + 255) >> 8;                // 391
    const int nbNode    = (N * 64 + 255) / 256;          // wave = node

    _Float16* fwb1 = fw;                 // L1 wb
    _Float16* fwn1 = fw + 4096;          // L2 wa
    _Float16* fwb2 = fw + 2 * 4096;      // L2 wb
    _Float16* fwn2 = fw + 3 * 4096;      // L3 wa
    _Float16* fwb3 = fw + 4 * 4096;      // L3 wb

    const int nGptrBlocks = (N + 255) / 256;             // 391
    const int nPreBlocks  = 2048 - NBLK - 5 - nGptrBlocks; // 1396

    // ---- fused setup: hist || wfrag || gptr || pre ----
    setup_kernel<<<2048, 256, 0, stream>>>(dst, ghist, E, chunk,
        yh + (size_t)N * 64, batch, gptr, N, G,
        x, p[0], yh, p[6], p[8], p[14], p[16], p[22], fw,
        nGptrBlocks, nPreBlocks);

    // ---- CSR build ----
    scan_block_g<<<nbScanB, 256, 0, stream>>>(ghist, bsum, nscan);
    bin_fill_kernel<<<NBLK, 256, 0, stream>>>(src, dst, ghist, bsum, pairs, E, chunk);
    csr_sort_kernel<<<nbuckUsed, 256, 0, stream>>>(pairs, bsum, col, rp, N, E, nbuckUsed);

    // ---- layer 1 ----
    agg_kernel<<<nbNode, 256, 0, stream>>>(yh, rp, col, p[1], p[2], p[3], p[4], p[5], th, N);
    mlp_mfma_kernel<false><<<512, 256, 0, stream>>>(th, fwb1, p[7], fwn1, yh, N);
    // ---- layer 2 ----
    agg_kernel<<<nbNode, 256, 0, stream>>>(yh, rp, col, p[9], p[10], p[11], p[12], p[13], th, N);
    mlp_mfma_kernel<false><<<512, 256, 0, stream>>>(th, fwb2, p[15], fwn2, yh, N);
    // ---- layer 3 ----
    agg_kernel<<<nbNode, 256, 0, stream>>>(yh, rp, col, p[17], p[18], p[19], p[20], p[21], th, N);
    mlp_mfma_kernel<true><<<512, 256, 0, stream>>>(th, fwb3, p[23], nullptr, h3h, N);

    // ---- fused pool + head ----
    pool_head_kernel<<<G, 64, 0, stream>>>(h3h, gptr,
        p[24], p[25], p[26], p[27], (float*)d_out, G);
}

// Round 13
// 197.604 us; speedup vs baseline: 1.0593x; 1.0593x over previous
//
#include <hip/hip_runtime.h>

// GIN forward: transformed-space linearity (y = h@wa; agg@wa = y_self + sum y_nbr)
// fp16 activation tables (y, t, z, h3), CSR via bucket binning + packed
// counting sort, wave-per-node gather agg (16-deep) with fused BN+ReLU,
// MFMA-f16 MLP with pre-fragmented weights (grid 1024), per-graph fused
// pool+head (8-deep). N=100000, E=1200000, DIM=64, G=1000, IN=11.

#define BN_EPS 1e-5f
#define NBUCK 512
#define NBLK  256

typedef __attribute__((ext_vector_type(8))) _Float16 half8v;  // 8 f16 (4 VGPRs)
typedef __attribute__((ext_vector_type(4))) float float4v;    // 4 fp32 acc

// ------ binning histogram (bucket-major) + fused zero of pad row -----------
__global__ __launch_bounds__(256)
void bin_hist_kernel(const int* __restrict__ dst, int* __restrict__ ghist,
                     int E, int chunk, _Float16* __restrict__ yrow) {
    __shared__ int h[NBUCK];
    const int tid = threadIdx.x, blk = blockIdx.x;
    if (blk == 0 && tid < 64) yrow[tid] = (_Float16)0.f;

    for (int u = tid; u < NBUCK; u += 256) h[u] = 0;
    __syncthreads();
    const int e0 = blk * chunk, e1 = min(E, e0 + chunk);
    for (int e = e0 + tid; e < e1; e += 256)
        atomicAdd(&h[dst[e] >> 8], 1);
    __syncthreads();
    for (int u = tid; u < NBUCK; u += 256)
        ghist[u * NBLK + blk] = h[u];
}

// ---------------- hierarchical exclusive scan ------------------------------
__global__ __launch_bounds__(256)
void scan_block_g(int* __restrict__ a, int* __restrict__ bsum, int n) {
    __shared__ int s[256];
    int i = blockIdx.x * 256 + threadIdx.x;
    int v = (i < n) ? a[i] : 0;
    s[threadIdx.x] = v;
    __syncthreads();
    for (int off = 1; off < 256; off <<= 1) {
        int t = (threadIdx.x >= off) ? s[threadIdx.x - off] : 0;
        __syncthreads();
        s[threadIdx.x] += t;
        __syncthreads();
    }
    if (i < n) a[i] = s[threadIdx.x] - v;
    if (threadIdx.x == 255) bsum[blockIdx.x] = s[255];
}

__global__ __launch_bounds__(512)
void scan_top_kernel(int* bsum, int nb) {
    __shared__ int s[512];
    int v = (threadIdx.x < nb) ? bsum[threadIdx.x] : 0;
    s[threadIdx.x] = v;
    __syncthreads();
    for (int off = 1; off < 512; off <<= 1) {
        int t = (threadIdx.x >= off) ? s[threadIdx.x - off] : 0;
        __syncthreads();
        s[threadIdx.x] += t;
        __syncthreads();
    }
    if (threadIdx.x < nb) bsum[threadIdx.x] = s[threadIdx.x] - v;
}

// ------- bin fill: block-local LDS cursors -> clustered packed writes ------
// packed pair: (dstLocal << 24) | src   (src < 2^24)
__global__ __launch_bounds__(256)
void bin_fill_kernel(const int* __restrict__ src, const int* __restrict__ dst,
                     const int* __restrict__ ghist, const int* __restrict__ bsum,
                     unsigned* __restrict__ pairs, int E, int chunk) {
    __shared__ int cur[NBUCK];
    const int tid = threadIdx.x, blk = blockIdx.x;
    for (int u = tid; u < NBUCK; u += 256)
        cur[u] = ghist[u * NBLK + blk] + bsum[u];
    __syncthreads();
    const int e0 = blk * chunk, e1 = min(E, e0 + chunk);
    for (int e = e0 + tid; e < e1; e += 256) {
        int d = dst[e];
        int pos = atomicAdd(&cur[d >> 8], 1);
        pairs[pos] = ((unsigned)(d & 255) << 24) | (unsigned)src[e];
    }
}

// ------- per-bucket counting sort -> per-node CSR (col, rp) ----------------
__global__ __launch_bounds__(256)
void csr_sort_kernel(const unsigned* __restrict__ pairs, const int* __restrict__ bsum,
                     int* __restrict__ col, int* __restrict__ rp,
                     int N, int E, int nbuckUsed) {
    __shared__ int cnt[256];
    __shared__ int cur[256];
    const int u = blockIdx.x, tid = threadIdx.x;
    const int base = bsum[u];
    const int end  = (u == NBUCK - 1) ? E : bsum[u + 1];
    const int node0 = u << 8;
    const int rows = min(256, N - node0);

    cnt[tid] = 0;
    __syncthreads();
    for (int e = base + tid; e < end; e += 256)
        atomicAdd(&cnt[pairs[e] >> 24], 1);
    __syncthreads();
    int own = cnt[tid];
    __syncthreads();
    cnt[tid] = own;
    __syncthreads();
    for (int off = 1; off < 256; off <<= 1) {
        int t = (tid >= off) ? cnt[tid - off] : 0;
        __syncthreads();
        cnt[tid] += t;
        __syncthreads();
    }
    const int excl = cnt[tid] - own;
    if (tid < rows) rp[node0 + tid] = base + excl;
    if (tid == 0 && u == nbuckUsed - 1) rp[N] = E;
    cur[tid] = base + excl;
    __syncthreads();
    for (int e = base + tid; e < end; e += 256) {
        unsigned p = pairs[e];
        int pos = atomicAdd(&cur[p >> 24], 1);
        col[pos] = (int)(p & 0xFFFFFF);
    }
}

// ------- graph boundaries: gptr[g] = first node of graph g (batch sorted) --
__global__ __launch_bounds__(256)
void gptr_kernel(const int* __restrict__ batch, int* __restrict__ gptr,
                 int n, int G) {
    int i = blockIdx.x * 256 + threadIdx.x;
    if (i >= n) return;
    int b = batch[i];
    int bprev = (i == 0) ? -1 : batch[i - 1];
    for (int g = bprev + 1; g <= b; ++g) gptr[g] = i;
    if (i == n - 1)
        for (int g = b + 1; g <= G; ++g) gptr[g] = n;
}

// ------- weight fragmenting: fp32 64x64 -> fp16 B-fragment order -----------
__global__ __launch_bounds__(256)
void wfrag_kernel(const float* __restrict__ w0, const float* __restrict__ w1,
                  const float* __restrict__ w2, const float* __restrict__ w3,
                  const float* __restrict__ w4, _Float16* __restrict__ out) {
    const float* w = (blockIdx.x == 0) ? w0 : (blockIdx.x == 1) ? w1 :
                     (blockIdx.x == 2) ? w2 : (blockIdx.x == 3) ? w3 : w4;
    _Float16* o = out + (size_t)blockIdx.x * 4096;
    const int lane = threadIdx.x & 63;
    const int cb   = threadIdx.x >> 6;
    const int half = lane >> 4, sub = lane & 15;
    #pragma unroll
    for (int it = 0; it < 2; ++it) {
        int c = cb + 4 * it;             // 0..7 = kk*4 + nt
        int kk = c >> 2, nt = c & 3;
        _Float16 f[8];
        #pragma unroll
        for (int j = 0; j < 8; ++j)
            f[j] = (_Float16)w[(kk * 32 + half * 8 + j) * 64 + nt * 16 + sub];
        *(half8v*)&o[((size_t)c * 64 + lane) * 8] = *(half8v*)f;
    }
}

// ---------------- pre-transform: yh = f16(x @ w1a) ----------------
__global__ __launch_bounds__(256)
void pre_kernel(const float* __restrict__ x, const float* __restrict__ wa,
                _Float16* __restrict__ yh, int n) {
    __shared__ float s_wa[11 * 64];
    __shared__ float s_row[4][11];
    const int tid = threadIdx.x;
    const int lane = tid & 63;
    const int local = tid >> 6;
    for (int i = tid; i < 11 * 64; i += 256) s_wa[i] = wa[i];
    __syncthreads();
    const int groups = (n + 3) >> 2;
    for (int grp = blockIdx.x; grp < groups; grp += gridDim.x) {
        const int node = grp * 4 + local;
        if (node >= n) continue;
        if (lane < 11) s_row[local][lane] = x[(size_t)node * 11 + lane];
        float acc = 0.f;
        #pragma unroll
        for (int k = 0; k < 11; ++k)
            acc = fmaf(s_row[local][k], s_wa[k * 64 + lane], acc);
        yh[((size_t)node << 6) + lane] = (_Float16)acc;
    }
}

// -- aggregate + BN + ReLU: t[i] = relu(bn(y[i] + sum_nbr y[j]) + ba) -------
__global__ __launch_bounds__(256, 8)
void agg_kernel(const _Float16* __restrict__ yh, const int* __restrict__ rp,
                const int* __restrict__ col,
                const float* __restrict__ ba,
                const float* __restrict__ gam, const float* __restrict__ bet,
                const float* __restrict__ rm, const float* __restrict__ rv,
                _Float16* __restrict__ th, int n) {
    int node = __builtin_amdgcn_readfirstlane(
        (int)((blockIdx.x * 256 + threadIdx.x) >> 6));
    if (node >= n) return;
    const int lane = threadIdx.x & 63;
    const int beg = rp[node], end = rp[node + 1];
    float agg = (float)yh[((size_t)node << 6) + lane];
    int i = beg;
    const int end16 = beg + ((end - beg) & ~15);
    for (; i < end16; i += 16) {
        int c[16];
        float v[16];
        #pragma unroll
        for (int j = 0; j < 16; ++j) c[j] = col[i + j];
        #pragma unroll
        for (int j = 0; j < 16; ++j) v[j] = (float)yh[((size_t)c[j] << 6) + lane];
        #pragma unroll
        for (int j = 0; j < 16; ++j) agg += v[j];
    }
    if (i < end) {
        int c[16];
        float v[16];
        #pragma unroll
        for (int j = 0; j < 16; ++j) c[j] = (i + j < end) ? col[i + j] : n;
        #pragma unroll
        for (int j = 0; j < 16; ++j) v[j] = (float)yh[((size_t)c[j] << 6) + lane];
        #pragma unroll
        for (int j = 0; j < 16; ++j) agg += v[j];
    }
    const float s = gam[lane] * rsqrtf(rv[lane] + BN_EPS);
    const float sh = bet[lane] - rm[lane] * s + ba[lane] * s;
    th[((size_t)node << 6) + lane] = (_Float16)fmaxf(fmaf(agg, s, sh), 0.f);
}

// ------------- MFMA MLP: z=relu(t@wb+bb); y'=f16(z@wn) / h3=f16(z) ---------
template<bool LAST>
__global__ __launch_bounds__(256, 2)
void mlp_mfma_kernel(const _Float16* __restrict__ th,   // [n,64] t fp16
                     const _Float16* __restrict__ fwb,  // [8][64][8] frag
                     const float* __restrict__ bb,
                     const _Float16* __restrict__ fwn,  // [8][64][8] frag
                     _Float16* __restrict__ outh, int n) {
    __shared__ _Float16 zt[4][16][72];   // per-wave z tile, 144B stride

    const int tid  = threadIdx.x;
    const int lane = tid & 63;
    const int w    = tid >> 6;
    const int half = lane >> 4;    // k-group / row-group
    const int sub  = lane & 15;    // row (A) / col (C)

    half8v wbf[2][4];
    #pragma unroll
    for (int kk = 0; kk < 2; ++kk)
        #pragma unroll
        for (int nt = 0; nt < 4; ++nt)
            wbf[kk][nt] = *(const half8v*)&fwb[(((size_t)(kk * 4 + nt)) * 64 + lane) * 8];
    half8v wnf[LAST ? 1 : 2][4];
    if (!LAST) {
        #pragma unroll
        for (int kk = 0; kk < 2; ++kk)
            #pragma unroll
            for (int nt = 0; nt < 4; ++nt)
                wnf[kk][nt] = *(const half8v*)&fwn[(((size_t)(kk * 4 + nt)) * 64 + lane) * 8];
    }
    float bbr[4];
    #pragma unroll
    for (int nt = 0; nt < 4; ++nt) bbr[nt] = bb[nt * 16 + sub];

    const int ngroups = (n + 15) >> 4;
    const int stride = gridDim.x * 4;
    for (int group = blockIdx.x * 4 + w; group < ngroups; group += stride) {
        const int node0 = group << 4;
        int mrow = node0 + sub;
        if (mrow >= n) mrow = n - 1;              // stores are guarded

        half8v at[2];
        #pragma unroll
        for (int kk = 0; kk < 2; ++kk)
            at[kk] = *(const half8v*)&th[((size_t)mrow << 6) + kk * 32 + half * 8];

        float4v accz[4];
        #pragma unroll
        for (int nt = 0; nt < 4; ++nt) {
            float4v c = {0.f, 0.f, 0.f, 0.f};
            c = __builtin_amdgcn_mfma_f32_16x16x32_f16(at[0], wbf[0][nt], c, 0, 0, 0);
            c = __builtin_amdgcn_mfma_f32_16x16x32_f16(at[1], wbf[1][nt], c, 0, 0, 0);
            accz[nt] = c;
        }

        if (LAST) {
            #pragma unroll
            for (int nt = 0; nt < 4; ++nt)
                #pragma unroll
                for (int r = 0; r < 4; ++r) {
                    int m = node0 + half * 4 + r;
                    if (m < n)
                        outh[((size_t)m << 6) + nt * 16 + sub] =
                            (_Float16)fmaxf(accz[nt][r] + bbr[nt], 0.f);
                }
        } else {
            #pragma unroll
            for (int nt = 0; nt < 4; ++nt)
                #pragma unroll
                for (int r = 0; r < 4; ++r)
                    zt[w][half * 4 + r][nt * 16 + sub] =
                        (_Float16)fmaxf(accz[nt][r] + bbr[nt], 0.f);
            asm volatile("s_waitcnt lgkmcnt(0)" ::: "memory");
            __builtin_amdgcn_sched_barrier(0);
            half8v az[2];
            #pragma unroll
            for (int kk = 0; kk < 2; ++kk)
                az[kk] = *(const half8v*)&zt[w][sub][kk * 32 + half * 8];

            #pragma unroll
            for (int nt = 0; nt < 4; ++nt) {
                float4v c = {0.f, 0.f, 0.f, 0.f};
                c = __builtin_amdgcn_mfma_f32_16x16x32_f16(az[0], wnf[0][nt], c, 0, 0, 0);
                c = __builtin_amdgcn_mfma_f32_16x16x32_f16(az[1], wnf[1][nt], c, 0, 0, 0);
                #pragma unroll
                for (int r = 0; r < 4; ++r) {
                    int m = node0 + half * 4 + r;
                    if (m < n)
                        outh[((size_t)m << 6) + nt * 16 + sub] = (_Float16)c[r];
                }
            }
        }
    }
}

// ------- fused pool+head: block = graph; pool rows (8-deep), head math -----
__global__ __launch_bounds__(64)
void pool_head_kernel(const _Float16* __restrict__ h, const int* __restrict__ gptr,
                      const float* __restrict__ lw1, const float* __restrict__ lb1,
                      const float* __restrict__ lw2, const float* __restrict__ lb2,
                      float* __restrict__ out, int G) {
    __shared__ float s_row[64];
    const int g = blockIdx.x;
    if (g >= G) return;
    const int d = threadIdx.x;
    const int beg = gptr[g], end = gptr[g + 1];

    float acc = 0.f;
    int i = beg;
    const int end8 = beg + ((end - beg) & ~7);
    for (; i < end8; i += 8) {
        float v[8];
        #pragma unroll
        for (int j = 0; j < 8; ++j)
            v[j] = (float)h[((size_t)(i + j) << 6) + d];
        #pragma unroll
        for (int j = 0; j < 8; ++j) acc += v[j];
    }
    for (; i < end; ++i) acc += (float)h[((size_t)i << 6) + d];

    s_row[d] = acc;
    __syncthreads();

    float z = lb1[d];
    #pragma unroll 8
    for (int k = 0; k < 64; ++k)
        z = fmaf(s_row[k], lw1[k * 64 + d], z);
    z = fmaxf(z, 0.f);
    float r = z * lw2[d];
    #pragma unroll
    for (int off = 32; off > 0; off >>= 1)
        r += __shfl_down(r, off, 64);
    if (d == 0) out[g] = r + lb2[0];
}

extern "C" void kernel_launch(void* const* d_in, const int* in_sizes, int n_in,
                              void* d_out, int out_size, void* d_ws, size_t ws_size,
                              hipStream_t stream) {
    const float* x    = (const float*)d_in[0];
    const int* ei     = (const int*)d_in[1];
    const int* batch  = (const int*)d_in[2];
    const int N = in_sizes[0] / 11;
    const int E = in_sizes[1] / 2;
    const int G = out_size;
    const int* src = ei;
    const int* dst = ei + E;

    const float* p[28];
    for (int i = 0; i < 28; ++i) p[i] = (const float*)d_in[3 + i];
    // p[0..7]=L1 {wa,ba,g,be,m,v,wb,bb}, p[8..15]=L2, p[16..23]=L3
    // p[24]=lw1 p[25]=lb1 p[26]=lw2 p[27]=lb2

    _Float16* yh  = (_Float16*)d_ws;                     // [(N+1),64] fp16 y
    _Float16* th  = yh + ((size_t)N + 1) * 64;           // [N,64] fp16 t
    _Float16* h3h = th + (size_t)N * 64;                 // [N,64] fp16 h3
    _Float16* fw  = h3h + (size_t)N * 64;                // [5*4096] weight frags
    int*   ghist  = (int*)(fw + 5 * 4096);               // [NBUCK*NBLK]
    int*   bsum   = ghist + NBUCK * NBLK;                // [512]
    int*   rp     = bsum + 512;                          // [N+1]
    int*   gptr   = rp + N + 1;                          // [G+1]
    int*   col    = gptr + G + 1;                        // [E]
    unsigned* pairs = (unsigned*)(col + E);              // [E] packed

    const int chunk     = (E + NBLK - 1) / NBLK;
    const int nscan     = NBUCK * NBLK;
    const int nbScanB   = nscan / 256;                   // 512
    const int nbuckUsed = (N + 255) >> 8;                // 391
    const int nbNode    = (N * 64 + 255) / 256;          // wave = node

    _Float16* fwb1 = fw;                 // L1 wb
    _Float16* fwn1 = fw + 4096;          // L2 wa
    _Float16* fwb2 = fw + 2 * 4096;      // L2 wb
    _Float16* fwn2 = fw + 3 * 4096;      // L3 wa
    _Float16* fwb3 = fw + 4 * 4096;      // L3 wb

    // ---- CSR build (+fused zero of pad row) ----
    bin_hist_kernel<<<NBLK, 256, 0, stream>>>(dst, ghist, E, chunk,
                                              yh + (size_t)N * 64);
    scan_block_g<<<nbScanB, 256, 0, stream>>>(ghist, bsum, nscan);
    scan_top_kernel<<<1, 512, 0, stream>>>(bsum, nbScanB);
    bin_fill_kernel<<<NBLK, 256, 0, stream>>>(src, dst, ghist, bsum, pairs, E, chunk);
    csr_sort_kernel<<<nbuckUsed, 256, 0, stream>>>(pairs, bsum, col, rp, N, E, nbuckUsed);

    // ---- graph boundaries + weight fragments + pre-transform ----
    gptr_kernel<<<(N + 255) / 256, 256, 0, stream>>>(batch, gptr, N, G);
    wfrag_kernel<<<5, 256, 0, stream>>>(p[6], p[8], p[14], p[16], p[22], fw);
    pre_kernel<<<2048, 256, 0, stream>>>(x, p[0], yh, N);

    // ---- layer 1 ----
    agg_kernel<<<nbNode, 256, 0, stream>>>(yh, rp, col, p[1], p[2], p[3], p[4], p[5], th, N);
    mlp_mfma_kernel<false><<<1024, 256, 0, stream>>>(th, fwb1, p[7], fwn1, yh, N);
    // ---- layer 2 ----
    agg_kernel<<<nbNode, 256, 0, stream>>>(yh, rp, col, p[9], p[10], p[11], p[12], p[13], th, N);
    mlp_mfma_kernel<false><<<1024, 256, 0, stream>>>(th, fwb2, p[15], fwn2, yh, N);
    // ---- layer 3 ----
    agg_kernel<<<nbNode, 256, 0, stream>>>(yh, rp, col, p[17], p[18], p[19], p[20], p[21], th, N);
    mlp_mfma_kernel<true><<<1024, 256, 0, stream>>>(th, fwb3, p[23], nullptr, h3h, N);

    // ---- fused pool + head ----
    pool_head_kernel<<<G, 64, 0, stream>>>(h3h, gptr,
        p[24], p[25], p[26], p[27], (float*)d_out, G);
}

// Round 14
// 184.138 us; speedup vs baseline: 1.1368x; 1.0731x over previous
//
#include <hip/hip_runtime.h>

// GIN forward: transformed-space linearity (y = h@wa; agg@wa = y_self + sum y_nbr)
// fp16 activation tables (y, t, z, h3), CSR via bucket binning + packed
// counting sort, 4-node/wave 16-lane-group gather agg (32 rows in flight)
// with fused BN+ReLU, MFMA-f16 MLP with pre-fragmented weights, per-graph
// fused pool+head. N=100000, E=1200000, DIM=64, G=1000, IN=11.

#define BN_EPS 1e-5f
#define NBUCK 512
#define NBLK  256

typedef __attribute__((ext_vector_type(8))) _Float16 half8v;  // 8 f16 (4 VGPRs)
typedef __attribute__((ext_vector_type(4))) _Float16 half4v;  // 4 f16 (2 VGPRs)
typedef __attribute__((ext_vector_type(4))) float float4v;    // 4 fp32 acc

// ------ binning histogram (bucket-major) + fused zero of pad row -----------
__global__ __launch_bounds__(256)
void bin_hist_kernel(const int* __restrict__ dst, int* __restrict__ ghist,
                     int E, int chunk, _Float16* __restrict__ yrow) {
    __shared__ int h[NBUCK];
    const int tid = threadIdx.x, blk = blockIdx.x;
    if (blk == 0 && tid < 64) yrow[tid] = (_Float16)0.f;

    for (int u = tid; u < NBUCK; u += 256) h[u] = 0;
    __syncthreads();
    const int e0 = blk * chunk, e1 = min(E, e0 + chunk);
    for (int e = e0 + tid; e < e1; e += 256)
        atomicAdd(&h[dst[e] >> 8], 1);
    __syncthreads();
    for (int u = tid; u < NBUCK; u += 256)
        ghist[u * NBLK + blk] = h[u];
}

// ---------------- hierarchical exclusive scan ------------------------------
__global__ __launch_bounds__(256)
void scan_block_g(int* __restrict__ a, int* __restrict__ bsum, int n) {
    __shared__ int s[256];
    int i = blockIdx.x * 256 + threadIdx.x;
    int v = (i < n) ? a[i] : 0;
    s[threadIdx.x] = v;
    __syncthreads();
    for (int off = 1; off < 256; off <<= 1) {
        int t = (threadIdx.x >= off) ? s[threadIdx.x - off] : 0;
        __syncthreads();
        s[threadIdx.x] += t;
        __syncthreads();
    }
    if (i < n) a[i] = s[threadIdx.x] - v;
    if (threadIdx.x == 255) bsum[blockIdx.x] = s[255];
}

__global__ __launch_bounds__(512)
void scan_top_kernel(int* bsum, int nb) {
    __shared__ int s[512];
    int v = (threadIdx.x < nb) ? bsum[threadIdx.x] : 0;
    s[threadIdx.x] = v;
    __syncthreads();
    for (int off = 1; off < 512; off <<= 1) {
        int t = (threadIdx.x >= off) ? s[threadIdx.x - off] : 0;
        __syncthreads();
        s[threadIdx.x] += t;
        __syncthreads();
    }
    if (threadIdx.x < nb) bsum[threadIdx.x] = s[threadIdx.x] - v;
}

// ------- bin fill: block-local LDS cursors -> clustered packed writes ------
// packed pair: (dstLocal << 24) | src   (src < 2^24)
__global__ __launch_bounds__(256)
void bin_fill_kernel(const int* __restrict__ src, const int* __restrict__ dst,
                     const int* __restrict__ ghist, const int* __restrict__ bsum,
                     unsigned* __restrict__ pairs, int E, int chunk) {
    __shared__ int cur[NBUCK];
    const int tid = threadIdx.x, blk = blockIdx.x;
    for (int u = tid; u < NBUCK; u += 256)
        cur[u] = ghist[u * NBLK + blk] + bsum[u];
    __syncthreads();
    const int e0 = blk * chunk, e1 = min(E, e0 + chunk);
    for (int e = e0 + tid; e < e1; e += 256) {
        int d = dst[e];
        int pos = atomicAdd(&cur[d >> 8], 1);
        pairs[pos] = ((unsigned)(d & 255) << 24) | (unsigned)src[e];
    }
}

// ------- per-bucket counting sort -> per-node CSR (col, rp) ----------------
__global__ __launch_bounds__(256)
void csr_sort_kernel(const unsigned* __restrict__ pairs, const int* __restrict__ bsum,
                     int* __restrict__ col, int* __restrict__ rp,
                     int N, int E, int nbuckUsed) {
    __shared__ int cnt[256];
    __shared__ int cur[256];
    const int u = blockIdx.x, tid = threadIdx.x;
    const int base = bsum[u];
    const int end  = (u == NBUCK - 1) ? E : bsum[u + 1];
    const int node0 = u << 8;
    const int rows = min(256, N - node0);

    cnt[tid] = 0;
    __syncthreads();
    for (int e = base + tid; e < end; e += 256)
        atomicAdd(&cnt[pairs[e] >> 24], 1);
    __syncthreads();
    int own = cnt[tid];
    __syncthreads();
    cnt[tid] = own;
    __syncthreads();
    for (int off = 1; off < 256; off <<= 1) {
        int t = (tid >= off) ? cnt[tid - off] : 0;
        __syncthreads();
        cnt[tid] += t;
        __syncthreads();
    }
    const int excl = cnt[tid] - own;
    if (tid < rows) rp[node0 + tid] = base + excl;
    if (tid == 0 && u == nbuckUsed - 1) rp[N] = E;
    cur[tid] = base + excl;
    __syncthreads();
    for (int e = base + tid; e < end; e += 256) {
        unsigned p = pairs[e];
        int pos = atomicAdd(&cur[p >> 24], 1);
        col[pos] = (int)(p & 0xFFFFFF);
    }
}

// ------- graph boundaries: gptr[g] = first node of graph g (batch sorted) --
__global__ __launch_bounds__(256)
void gptr_kernel(const int* __restrict__ batch, int* __restrict__ gptr,
                 int n, int G) {
    int i = blockIdx.x * 256 + threadIdx.x;
    if (i >= n) return;
    int b = batch[i];
    int bprev = (i == 0) ? -1 : batch[i - 1];
    for (int g = bprev + 1; g <= b; ++g) gptr[g] = i;
    if (i == n - 1)
        for (int g = b + 1; g <= G; ++g) gptr[g] = n;
}

// ------- weight fragmenting: fp32 64x64 -> fp16 B-fragment order -----------
__global__ __launch_bounds__(256)
void wfrag_kernel(const float* __restrict__ w0, const float* __restrict__ w1,
                  const float* __restrict__ w2, const float* __restrict__ w3,
                  const float* __restrict__ w4, _Float16* __restrict__ out) {
    const float* w = (blockIdx.x == 0) ? w0 : (blockIdx.x == 1) ? w1 :
                     (blockIdx.x == 2) ? w2 : (blockIdx.x == 3) ? w3 : w4;
    _Float16* o = out + (size_t)blockIdx.x * 4096;
    const int lane = threadIdx.x & 63;
    const int cb   = threadIdx.x >> 6;
    const int half = lane >> 4, sub = lane & 15;
    #pragma unroll
    for (int it = 0; it < 2; ++it) {
        int c = cb + 4 * it;             // 0..7 = kk*4 + nt
        int kk = c >> 2, nt = c & 3;
        _Float16 f[8];
        #pragma unroll
        for (int j = 0; j < 8; ++j)
            f[j] = (_Float16)w[(kk * 32 + half * 8 + j) * 64 + nt * 16 + sub];
        *(half8v*)&o[((size_t)c * 64 + lane) * 8] = *(half8v*)f;
    }
}

// ---------------- pre-transform: yh = f16(x @ w1a) ----------------
__global__ __launch_bounds__(256)
void pre_kernel(const float* __restrict__ x, const float* __restrict__ wa,
                _Float16* __restrict__ yh, int n) {
    __shared__ float s_wa[11 * 64];
    __shared__ float s_row[4][11];
    const int tid = threadIdx.x;
    const int lane = tid & 63;
    const int local = tid >> 6;
    for (int i = tid; i < 11 * 64; i += 256) s_wa[i] = wa[i];
    __syncthreads();
    const int groups = (n + 3) >> 2;
    for (int grp = blockIdx.x; grp < groups; grp += gridDim.x) {
        const int node = grp * 4 + local;
        if (node >= n) continue;
        if (lane < 11) s_row[local][lane] = x[(size_t)node * 11 + lane];
        float acc = 0.f;
        #pragma unroll
        for (int k = 0; k < 11; ++k)
            acc = fmaf(s_row[local][k], s_wa[k * 64 + lane], acc);
        yh[((size_t)node << 6) + lane] = (_Float16)acc;
    }
}

// -- aggregate + BN + ReLU: t[i] = relu(bn(y[i] + sum_nbr y[j]) + ba) -------
// 4 nodes/wave, 16 lanes/node (lane reads 4 fp16 = 8B of its node's row).
// 8-deep unroll -> 32 rows in flight per wave. Finished groups pad-gather
// the zero row at index n (hot line).
__global__ __launch_bounds__(256, 8)
void agg_kernel(const _Float16* __restrict__ yh, const int* __restrict__ rp,
                const int* __restrict__ col,
                const float* __restrict__ ba,
                const float* __restrict__ gam, const float* __restrict__ bet,
                const float* __restrict__ rm, const float* __restrict__ rv,
                _Float16* __restrict__ th, int n) {
    const int wv   = (blockIdx.x << 2) | (threadIdx.x >> 6);  // wave id
    const int lane = threadIdx.x & 63;
    const int grp  = lane >> 4;          // 0..3: node within wave
    const int gl   = lane & 15;          // lane within group
    const int node = (wv << 2) | grp;
    if (node >= n) return;
    const int fo = gl << 2;              // feature offset (4 features/lane)

    const int beg = rp[node], end = rp[node + 1];

    half4v selfv = *(const half4v*)&yh[((size_t)node << 6) + fo];
    float a0 = (float)selfv[0], a1 = (float)selfv[1];
    float a2 = (float)selfv[2], a3 = (float)selfv[3];

    for (int i = beg; i < end; i += 8) {
        int c[8];
        half4v v[8];
        #pragma unroll
        for (int j = 0; j < 8; ++j) c[j] = (i + j < end) ? col[i + j] : n;
        #pragma unroll
        for (int j = 0; j < 8; ++j)
            v[j] = *(const half4v*)&yh[((size_t)c[j] << 6) + fo];
        #pragma unroll
        for (int j = 0; j < 8; ++j) {
            a0 += (float)v[j][0];
            a1 += (float)v[j][1];
            a2 += (float)v[j][2];
            a3 += (float)v[j][3];
        }
    }

    const float4 g4 = *(const float4*)&gam[fo];
    const float4 v4 = *(const float4*)&rv[fo];
    const float4 b4 = *(const float4*)&bet[fo];
    const float4 m4 = *(const float4*)&rm[fo];
    const float4 ba4 = *(const float4*)&ba[fo];
    const float s0 = g4.x * rsqrtf(v4.x + BN_EPS);
    const float s1 = g4.y * rsqrtf(v4.y + BN_EPS);
    const float s2 = g4.z * rsqrtf(v4.z + BN_EPS);
    const float s3 = g4.w * rsqrtf(v4.w + BN_EPS);
    half4v o;
    o[0] = (_Float16)fmaxf(fmaf(a0, s0, b4.x - m4.x * s0 + ba4.x * s0), 0.f);
    o[1] = (_Float16)fmaxf(fmaf(a1, s1, b4.y - m4.y * s1 + ba4.y * s1), 0.f);
    o[2] = (_Float16)fmaxf(fmaf(a2, s2, b4.z - m4.z * s2 + ba4.z * s2), 0.f);
    o[3] = (_Float16)fmaxf(fmaf(a3, s3, b4.w - m4.w * s3 + ba4.w * s3), 0.f);
    *(half4v*)&th[((size_t)node << 6) + fo] = o;
}

// ------------- MFMA MLP: z=relu(t@wb+bb); y'=f16(z@wn) / h3=f16(z) ---------
template<bool LAST>
__global__ __launch_bounds__(256, 2)
void mlp_mfma_kernel(const _Float16* __restrict__ th,   // [n,64] t fp16
                     const _Float16* __restrict__ fwb,  // [8][64][8] frag
                     const float* __restrict__ bb,
                     const _Float16* __restrict__ fwn,  // [8][64][8] frag
                     _Float16* __restrict__ outh, int n) {
    __shared__ _Float16 zt[4][16][72];   // per-wave z tile, 144B stride

    const int tid  = threadIdx.x;
    const int lane = tid & 63;
    const int w    = tid >> 6;
    const int half = lane >> 4;    // k-group / row-group
    const int sub  = lane & 15;    // row (A) / col (C)

    half8v wbf[2][4];
    #pragma unroll
    for (int kk = 0; kk < 2; ++kk)
        #pragma unroll
        for (int nt = 0; nt < 4; ++nt)
            wbf[kk][nt] = *(const half8v*)&fwb[(((size_t)(kk * 4 + nt)) * 64 + lane) * 8];
    half8v wnf[LAST ? 1 : 2][4];
    if (!LAST) {
        #pragma unroll
        for (int kk = 0; kk < 2; ++kk)
            #pragma unroll
            for (int nt = 0; nt < 4; ++nt)
                wnf[kk][nt] = *(const half8v*)&fwn[(((size_t)(kk * 4 + nt)) * 64 + lane) * 8];
    }
    float bbr[4];
    #pragma unroll
    for (int nt = 0; nt < 4; ++nt) bbr[nt] = bb[nt * 16 + sub];

    const int ngroups = (n + 15) >> 4;
    const int stride = gridDim.x * 4;
    for (int group = blockIdx.x * 4 + w; group < ngroups; group += stride) {
        const int node0 = group << 4;
        int mrow = node0 + sub;
        if (mrow >= n) mrow = n - 1;              // stores are guarded

        half8v at[2];
        #pragma unroll
        for (int kk = 0; kk < 2; ++kk)
            at[kk] = *(const half8v*)&th[((size_t)mrow << 6) + kk * 32 + half * 8];

        float4v accz[4];
        #pragma unroll
        for (int nt = 0; nt < 4; ++nt) {
            float4v c = {0.f, 0.f, 0.f, 0.f};
            c = __builtin_amdgcn_mfma_f32_16x16x32_f16(at[0], wbf[0][nt], c, 0, 0, 0);
            c = __builtin_amdgcn_mfma_f32_16x16x32_f16(at[1], wbf[1][nt], c, 0, 0, 0);
            accz[nt] = c;
        }

        if (LAST) {
            #pragma unroll
            for (int nt = 0; nt < 4; ++nt)
                #pragma unroll
                for (int r = 0; r < 4; ++r) {
                    int m = node0 + half * 4 + r;
                    if (m < n)
                        outh[((size_t)m << 6) + nt * 16 + sub] =
                            (_Float16)fmaxf(accz[nt][r] + bbr[nt], 0.f);
                }
        } else {
            #pragma unroll
            for (int nt = 0; nt < 4; ++nt)
                #pragma unroll
                for (int r = 0; r < 4; ++r)
                    zt[w][half * 4 + r][nt * 16 + sub] =
                        (_Float16)fmaxf(accz[nt][r] + bbr[nt], 0.f);
            asm volatile("s_waitcnt lgkmcnt(0)" ::: "memory");
            __builtin_amdgcn_sched_barrier(0);
            half8v az[2];
            #pragma unroll
            for (int kk = 0; kk < 2; ++kk)
                az[kk] = *(const half8v*)&zt[w][sub][kk * 32 + half * 8];

            #pragma unroll
            for (int nt = 0; nt < 4; ++nt) {
                float4v c = {0.f, 0.f, 0.f, 0.f};
                c = __builtin_amdgcn_mfma_f32_16x16x32_f16(az[0], wnf[0][nt], c, 0, 0, 0);
                c = __builtin_amdgcn_mfma_f32_16x16x32_f16(az[1], wnf[1][nt], c, 0, 0, 0);
                #pragma unroll
                for (int r = 0; r < 4; ++r) {
                    int m = node0 + half * 4 + r;
                    if (m < n)
                        outh[((size_t)m << 6) + nt * 16 + sub] = (_Float16)c[r];
                }
            }
        }
    }
}

// ------- fused pool+head: block = graph; pool rows (8-deep), head math -----
__global__ __launch_bounds__(64)
void pool_head_kernel(const _Float16* __restrict__ h, const int* __restrict__ gptr,
                      const float* __restrict__ lw1, const float* __restrict__ lb1,
                      const float* __restrict__ lw2, const float* __restrict__ lb2,
                      float* __restrict__ out, int G) {
    __shared__ float s_row[64];
    const int g = blockIdx.x;
    if (g >= G) return;
    const int d = threadIdx.x;
    const int beg = gptr[g], end = gptr[g + 1];

    float acc = 0.f;
    int i = beg;
    const int end8 = beg + ((end - beg) & ~7);
    for (; i < end8; i += 8) {
        float v[8];
        #pragma unroll
        for (int j = 0; j < 8; ++j)
            v[j] = (float)h[((size_t)(i + j) << 6) + d];
        #pragma unroll
        for (int j = 0; j < 8; ++j) acc += v[j];
    }
    for (; i < end; ++i) acc += (float)h[((size_t)i << 6) + d];

    s_row[d] = acc;
    __syncthreads();

    float z = lb1[d];
    #pragma unroll 8
    for (int k = 0; k < 64; ++k)
        z = fmaf(s_row[k], lw1[k * 64 + d], z);
    z = fmaxf(z, 0.f);
    float r = z * lw2[d];
    #pragma unroll
    for (int off = 32; off > 0; off >>= 1)
        r += __shfl_down(r, off, 64);
    if (d == 0) out[g] = r + lb2[0];
}

extern "C" void kernel_launch(void* const* d_in, const int* in_sizes, int n_in,
                              void* d_out, int out_size, void* d_ws, size_t ws_size,
                              hipStream_t stream) {
    const float* x    = (const float*)d_in[0];
    const int* ei     = (const int*)d_in[1];
    const int* batch  = (const int*)d_in[2];
    const int N = in_sizes[0] / 11;
    const int E = in_sizes[1] / 2;
    const int G = out_size;
    const int* src = ei;
    const int* dst = ei + E;

    const float* p[28];
    for (int i = 0; i < 28; ++i) p[i] = (const float*)d_in[3 + i];
    // p[0..7]=L1 {wa,ba,g,be,m,v,wb,bb}, p[8..15]=L2, p[16..23]=L3
    // p[24]=lw1 p[25]=lb1 p[26]=lw2 p[27]=lb2

    _Float16* yh  = (_Float16*)d_ws;                     // [(N+1),64] fp16 y
    _Float16* th  = yh + ((size_t)N + 1) * 64;           // [N,64] fp16 t
    _Float16* h3h = th + (size_t)N * 64;                 // [N,64] fp16 h3
    _Float16* fw  = h3h + (size_t)N * 64;                // [5*4096] weight frags
    int*   ghist  = (int*)(fw + 5 * 4096);               // [NBUCK*NBLK]
    int*   bsum   = ghist + NBUCK * NBLK;                // [512]
    int*   rp     = bsum + 512;                          // [N+1]
    int*   gptr   = rp + N + 1;                          // [G+1]
    int*   col    = gptr + G + 1;                        // [E]
    unsigned* pairs = (unsigned*)(col + E);              // [E] packed

    const int chunk     = (E + NBLK - 1) / NBLK;
    const int nscan     = NBUCK * NBLK;
    const int nbScanB   = nscan / 256;                   // 512
    const int nbuckUsed = (N + 255) >> 8;                // 391
    const int nWaves    = (N + 3) / 4;                   // 4 nodes per wave
    const int nbAgg     = (nWaves + 3) / 4;              // 4 waves per block

    _Float16* fwb1 = fw;                 // L1 wb
    _Float16* fwn1 = fw + 4096;          // L2 wa
    _Float16* fwb2 = fw + 2 * 4096;      // L2 wb
    _Float16* fwn2 = fw + 3 * 4096;      // L3 wa
    _Float16* fwb3 = fw + 4 * 4096;      // L3 wb

    // ---- CSR build (+fused zero of pad row) ----
    bin_hist_kernel<<<NBLK, 256, 0, stream>>>(dst, ghist, E, chunk,
                                              yh + (size_t)N * 64);
    scan_block_g<<<nbScanB, 256, 0, stream>>>(ghist, bsum, nscan);
    scan_top_kernel<<<1, 512, 0, stream>>>(bsum, nbScanB);
    bin_fill_kernel<<<NBLK, 256, 0, stream>>>(src, dst, ghist, bsum, pairs, E, chunk);
    csr_sort_kernel<<<nbuckUsed, 256, 0, stream>>>(pairs, bsum, col, rp, N, E, nbuckUsed);

    // ---- graph boundaries + weight fragments + pre-transform ----
    gptr_kernel<<<(N + 255) / 256, 256, 0, stream>>>(batch, gptr, N, G);
    wfrag_kernel<<<5, 256, 0, stream>>>(p[6], p[8], p[14], p[16], p[22], fw);
    pre_kernel<<<2048, 256, 0, stream>>>(x, p[0], yh, N);

    // ---- layer 1 ----
    agg_kernel<<<nbAgg, 256, 0, stream>>>(yh, rp, col, p[1], p[2], p[3], p[4], p[5], th, N);
    mlp_mfma_kernel<false><<<1024, 256, 0, stream>>>(th, fwb1, p[7], fwn1, yh, N);
    // ---- layer 2 ----
    agg_kernel<<<nbAgg, 256, 0, stream>>>(yh, rp, col, p[9], p[10], p[11], p[12], p[13], th, N);
    mlp_mfma_kernel<false><<<1024, 256, 0, stream>>>(th, fwb2, p[15], fwn2, yh, N);
    // ---- layer 3 ----
    agg_kernel<<<nbAgg, 256, 0, stream>>>(yh, rp, col, p[17], p[18], p[19], p[20], p[21], th, N);
    mlp_mfma_kernel<true><<<1024, 256, 0, stream>>>(th, fwb3, p[23], nullptr, h3h, N);

    // ---- fused pool + head ----
    pool_head_kernel<<<G, 64, 0, stream>>>(h3h, gptr,
        p[24], p[25], p[26], p[27], (float*)d_out, G);
}